// Round 12
// baseline (795.308 us; speedup 1.0000x reference)
//
#include <hip/hip_runtime.h>
#include <math.h>
#include <limits.h>

#define HH 1280
#define WW 1920
#define OUT_H 427
#define OUT_W 640
#define SENT 0x7fff7fff   // packed (r,c) sentinel: r=c=0x7fff

typedef short short2v __attribute__((ext_vector_type(2)));

// d^2 between packed cell a=(r<<16|c) and packed owner P=(pi<<16|pj).
// Exact int32: max real d^2 = 1279^2+1919^2 = 5.3e6; SENT d^2 ~ 1.94e9 < 2^31.
// SENT never beats a real cur and ties with SENT cur (strict <) -> reproduces
// the reference's "skip SENT cand / INT_MAX for SENT cur" bit-exactly.
__device__ __forceinline__ int dot22(int a, int P) {
#if __has_builtin(__builtin_amdgcn_sdot2)
    short2v s = __builtin_bit_cast(short2v, a) - __builtin_bit_cast(short2v, P);
    return __builtin_amdgcn_sdot2(s, s, 0, false);
#else
    int dr = (a >> 16) - (P >> 16);
    int dc = (short)a - (short)P;
    return dr * dr + dc * dc;
#endif
}
// strict-< pick with carried d^2(cur)
#define PICK(P, cur, dcur, cand)                    \
    {                                               \
        int _d = dot22((cand), (P));                \
        if (_d < (dcur)) { (cur) = (cand); (dcur) = _d; } \
    }

// ---------------- scatter: project points, atomicAdd depth ----------------
// Reproduces XLA CPU dot lowering bit-exactly: plain mul/add (no FMA),
// ascending-k accumulation, translation added after.
__global__ void scatter_k(const float* __restrict__ pts,
                          const float* __restrict__ pose,
                          const float* __restrict__ extr,
                          const float* __restrict__ intr,
                          float* __restrict__ depth, int N) {
    #pragma clang fp contract(off)
    int t = blockIdx.x * blockDim.x + threadIdx.x;
    int b = blockIdx.y;
    if (t >= N) return;
    const float* p = pts + ((long)b * N + t) * 3;
    float x = p[0], y = p[1], z = p[2];
    const float* P = pose + b * 16;
    const float* E = extr + b * 16;
    const float* K = intr + b * 9;
    float wx = ((x*P[0] + y*P[1]) + z*P[2]) + P[3];
    float wy = ((x*P[4] + y*P[5]) + z*P[6]) + P[7];
    float wz = ((x*P[8] + y*P[9]) + z*P[10]) + P[11];
    float cx = ((wx*E[0] + wy*E[1]) + wz*E[2]) + E[3];
    float cy = ((wx*E[4] + wy*E[5]) + wz*E[6]) + E[7];
    float cz = ((wx*E[8] + wy*E[9]) + wz*E[10]) + E[11];
    float px = (cx*K[0] + cy*K[1]) + cz*K[2];
    float py = (cx*K[3] + cy*K[4]) + cz*K[5];
    float pz = (cx*K[6] + cy*K[7]) + cz*K[8];
    float u = px / pz, v = py / pz;
    int r = (int)floorf(v), c = (int)floorf(u);
    if (r >= 0 && r < HH && c >= 0 && c < WW) {
        float dv = sqrtf((x*x + y*y) + z*z);
        atomicAdd(depth + ((long)b * HH + r) * WW + c, dv);
    }
}

// ========== fully-fused one-k-step JFA (R9 skeleton x R10 cheap pick) ==========
// Per output row i: stage 7 input rows i+(t-3)k (slot t=0..6) in LDS.
// G1 (dy=-k group, jfa3r tree) on rows slots 0..3 -> writeback;
// G2 (dy=0 group, jfa2r tree) row-local on slots 0..3 -> writeback;
// G3 (dy=+k group) for row i (slot map: i-s*k at slot 3-s) -> one store.
// OOB rows pinned SENT at stage and every writeback.
template <bool FIRST>
__global__ __launch_bounds__(512)
void fstep_k(const void* __restrict__ inp, int* __restrict__ out, int k) {
    __shared__ int rows[7][WW];
    int i = blockIdx.x, b = blockIdx.y;
    int tid = threadIdx.x;
    int rr[7];
    bool rOK[7];
    #pragma unroll
    for (int t = 0; t < 7; ++t) {
        rr[t] = i + (t - 3) * k;
        rOK[t] = (unsigned)rr[t] < (unsigned)HH;
    }
    // ---- stage ----
    if (tid < WW / 4) {
        if (FIRST) {
            const float* dep = (const float*)inp + (long)b * HH * WW;
            #pragma unroll
            for (int t = 0; t < 7; ++t) {
                int4 v;
                if (rOK[t]) {
                    float4 d = reinterpret_cast<const float4*>(dep + (long)rr[t] * WW)[tid];
                    int c0 = tid * 4, pb = rr[t] << 16;
                    v.x = (d.x != 0.0f) ? (pb | c0)       : SENT;
                    v.y = (d.y != 0.0f) ? (pb | (c0 + 1)) : SENT;
                    v.z = (d.z != 0.0f) ? (pb | (c0 + 2)) : SENT;
                    v.w = (d.w != 0.0f) ? (pb | (c0 + 3)) : SENT;
                } else { v.x = v.y = v.z = v.w = SENT; }
                reinterpret_cast<int4*>(rows[t])[tid] = v;
            }
        } else {
            const int* im = (const int*)inp + (long)b * HH * WW;
            #pragma unroll
            for (int t = 0; t < 7; ++t) {
                int4 v;
                if (rOK[t]) v = reinterpret_cast<const int4*>(im + (long)rr[t] * WW)[tid];
                else { v.x = v.y = v.z = v.w = SENT; }
                reinterpret_cast<int4*>(rows[t])[tid] = v;
            }
        }
    }
    __syncthreads();
    // ---- G1: dy=-k group on slots 0..3 (row r uses slots t0..t0+3) ----
    int g1[4][4];
    #pragma unroll
    for (int t0 = 0; t0 < 4; ++t0) {
        int r = rr[t0];
        bool rv1 = rOK[t0 + 1], rv2 = rOK[t0 + 2];
        #pragma unroll
        for (int u = 0; u < 4; ++u) {
            int j = tid + u * 512;
            int res = SENT;
            if (j < WW && rOK[t0]) {
                bool jk = (j + k < WW);
                int Pp = (r << 16) | j;
                int cur = rows[t0][j];
                int dcur = dot22(cur, Pp);
                int c1 = jk ? rows[t0 + 1][j + k] : SENT;
                PICK(Pp, cur, dcur, c1)
                int o1m = SENT;
                if (rv1) {
                    int Pm = ((r + k) << 16) | j;
                    int a = rows[t0 + 1][j];
                    int da = dot22(a, Pm);
                    int c2 = jk ? rows[t0 + 2][j + k] : SENT;
                    PICK(Pm, a, da, c2)
                    o1m = a;
                }
                PICK(Pp, cur, dcur, o1m)
                int o2q = SENT;
                int qj = j - k;
                if (rv1 && qj >= 0) {
                    int Pq = ((r + k) << 16) | qj;
                    int a0 = rows[t0 + 1][qj];
                    int d0 = dot22(a0, Pq);
                    PICK(Pq, a0, d0, rows[t0 + 2][j])
                    int a1 = SENT;
                    if (rv2) {
                        int Pq2 = ((r + 2 * k) << 16) | qj;
                        a1 = rows[t0 + 2][qj];
                        int d1 = dot22(a1, Pq2);
                        PICK(Pq2, a1, d1, rows[t0 + 3][j])
                    }
                    PICK(Pq, a0, d0, a1)
                    o2q = a0;
                }
                PICK(Pp, cur, dcur, o2q)
                res = cur;
            }
            g1[t0][u] = res;
        }
    }
    __syncthreads();
    #pragma unroll
    for (int t0 = 0; t0 < 4; ++t0)
        #pragma unroll
        for (int u = 0; u < 4; ++u) {
            int j = tid + u * 512;
            if (j < WW) rows[t0][j] = g1[t0][u];
        }
    __syncthreads();
    // ---- G2: dy=0 group, row-local on slots 0..3 ----
    int g2[4][4];
    #pragma unroll
    for (int t0 = 0; t0 < 4; ++t0) {
        int r = rr[t0];
        #pragma unroll
        for (int u = 0; u < 4; ++u) {
            int j = tid + u * 512;
            int res = SENT;
            if (j < WW && rOK[t0]) {
                int Pp = (r << 16) | j;
                int a = rows[t0][j];
                int cur = a;
                int dcur = dot22(cur, Pp);
                int apk = (j + k < WW) ? rows[t0][j + k] : SENT;
                PICK(Pp, cur, dcur, apk)
                int o1m = SENT;
                int qj = j - k;
                if (qj >= 0) {
                    int Pm = (r << 16) | qj;
                    int am = rows[t0][qj];
                    int dm = dot22(am, Pm);
                    PICK(Pm, am, dm, a)
                    o1m = am;
                }
                PICK(Pp, cur, dcur, o1m)
                res = cur;
            }
            g2[t0][u] = res;
        }
    }
    __syncthreads();
    #pragma unroll
    for (int t0 = 0; t0 < 4; ++t0)
        #pragma unroll
        for (int u = 0; u < 4; ++u) {
            int j = tid + u * 512;
            if (j < WW) rows[t0][j] = g2[t0][u];
        }
    __syncthreads();
    // ---- G3: dy=+k group for row i; G2 row i-s*k lives in slot 3-s ----
    int* orow = out + ((long)b * HH + i) * WW;
    bool rv1 = rOK[2], rv2 = rOK[1];  // rows i-k, i-2k
    #pragma unroll
    for (int u = 0; u < 4; ++u) {
        int j = tid + u * 512;
        if (j >= WW) continue;
        bool jk = (j + k < WW);
        int Pp = (i << 16) | j;
        int cur = rows[3][j];
        int dcur = dot22(cur, Pp);
        int c1 = jk ? rows[2][j + k] : SENT;
        PICK(Pp, cur, dcur, c1)
        int o1m = SENT;
        if (rv1) {
            int Pm = ((i - k) << 16) | j;
            int a = rows[2][j];
            int da = dot22(a, Pm);
            int c2 = jk ? rows[1][j + k] : SENT;
            PICK(Pm, a, da, c2)
            o1m = a;
        }
        PICK(Pp, cur, dcur, o1m)
        int o2q = SENT;
        int qj = j - k;
        if (rv1 && qj >= 0) {
            int Pq = ((i - k) << 16) | qj;
            int a0 = rows[2][qj];
            int d0 = dot22(a0, Pq);
            PICK(Pq, a0, d0, rows[1][j])
            int a1 = SENT;
            if (rv2) {
                int Pq2 = ((i - 2 * k) << 16) | qj;
                a1 = rows[1][qj];
                int d1 = dot22(a1, Pq2);
                PICK(Pq2, a1, d1, rows[0][j])
            }
            PICK(Pq, a0, d0, a1)
            o2q = a0;
        }
        PICK(Pp, cur, dcur, o2q)
        orow[j] = cur;
    }
}

// ------- fused compose + horizontal resize: one block per image row -------
__global__ __launch_bounds__(256)
void hresize_k(const float* __restrict__ depth,
               const int* __restrict__ nr,
               float* __restrict__ tmp) {
    __shared__ float fbuf[WW];
    __shared__ float dbuf[WW];
    int i = blockIdx.x, b = blockIdx.y;
    const float* dep = depth + (long)b * HH * WW;
    const float* drow = dep + (long)i * WW;
    const int* nrow = nr + ((long)b * HH + i) * WW;
    for (int j = threadIdx.x; j < WW; j += 256) {
        float dv = drow[j];
        float f, dist;
        if (dv != 0.0f) { f = dv; dist = 0.0f; }
        else {
            int nn = nrow[j];
            int rr, cc;
            if (nn == SENT) { rr = HH - 1; cc = WW - 1; }  // clip(BIG) path
            else { rr = nn >> 16; cc = nn & 0xffff; }
            f = dep[(long)rr * WW + cc];
            float drr = (float)i - (float)rr, dcc = (float)j - (float)cc;
            dist = sqrtf(drr * drr + dcc * dcc);
        }
        fbuf[j] = f; dbuf[j] = dist;
    }
    __syncthreads();
    const float inv = 3.0f;  // 1920/640
    for (int ow = threadIdx.x; ow < OUT_W; ow += 256) {
        float sf = (ow + 0.5f) * inv - 0.5f;
        int i0 = (int)ceilf(sf - inv);
        float a0 = 0.f, a1 = 0.f, wsum = 0.f;
        for (int k = 0; k < 7; ++k) {
            int iw = i0 + k;
            if (iw < 0 || iw >= WW) continue;
            float wgt = 1.0f - fabsf(sf - (float)iw) / inv;
            if (wgt <= 0.0f) continue;
            a0 += wgt * fbuf[iw]; a1 += wgt * dbuf[iw]; wsum += wgt;
        }
        long o = (((long)b * 2 + 0) * HH + i) * OUT_W + ow;
        tmp[o] = a0 / wsum;
        tmp[o + (long)HH * OUT_W] = a1 / wsum;
    }
}

// ---------------- vertical resize (H 1280->427) ----------------
__global__ void vresize_k(const float* __restrict__ tmp, float* __restrict__ out) {
    int ow = blockIdx.x * blockDim.x + threadIdx.x;
    int oh = blockIdx.y, bc = blockIdx.z;  // bc = b*2 + ch
    if (ow >= OUT_W) return;
    const float inv = (float)(1280.0 / 427.0);
    float sf = (oh + 0.5f) * inv - 0.5f;
    int i0 = (int)ceilf(sf - inv);
    float acc = 0.f, wsum = 0.f;
    const float* src = tmp + (long)bc * HH * OUT_W;
    for (int k = 0; k < 7; ++k) {
        int ih = i0 + k;
        if (ih < 0 || ih >= HH) continue;
        float wgt = 1.0f - fabsf(sf - (float)ih) / inv;
        if (wgt <= 0.0f) continue;
        acc += wgt * src[(long)ih * OUT_W + ow];
        wsum += wgt;
    }
    out[((long)bc * OUT_H + oh) * OUT_W + ow] = acc / wsum;
}

extern "C" void kernel_launch(void* const* d_in, const int* in_sizes, int n_in,
                              void* d_out, int out_size, void* d_ws, size_t ws_size,
                              hipStream_t stream) {
    const float* pts  = (const float*)d_in[0];
    const float* pose = (const float*)d_in[1];
    const float* extr = (const float*)d_in[2];
    const float* intr = (const float*)d_in[3];
    int B = in_sizes[1] / 16;
    int N = in_sizes[0] / (3 * B);

    char* ws = (char*)d_ws;
    size_t imgSz = (size_t)B * HH * WW;
    float* depth = (float*)ws;                  // B*H*W f32
    int*   nearA = (int*)(ws + imgSz * 4);      // B*H*W i32
    int*   nearB = (int*)(ws + imgSz * 8);      // B*H*W i32
    float* tmp   = (float*)(ws + imgSz * 12);   // B*2*H*OUT_W f32

    hipMemsetAsync(depth, 0, imgSz * sizeof(float), stream);

    dim3 bs(256);
    scatter_k<<<dim3((N + 255) / 256, B), bs, 0, stream>>>(pts, pose, extr, intr, depth, N);

    dim3 gr(HH, B);
    int* cur = nearA; int* nxt = nearB;
    // leading k=1 step, init fused into staging
    fstep_k<true><<<gr, 512, 0, stream>>>(depth, cur, 1);
    const int steps_rest[11] = {1024, 512, 256, 128, 64, 32, 16, 8, 4, 2, 1};
    for (int s = 0; s < 11; ++s) {
        fstep_k<false><<<gr, 512, 0, stream>>>(cur, nxt, steps_rest[s]);
        int* t2 = cur; cur = nxt; nxt = t2;
    }

    hresize_k<<<dim3(HH, B), bs, 0, stream>>>(depth, cur, tmp);
    vresize_k<<<dim3((OUT_W + 255) / 256, OUT_H, B * 2), bs, 0, stream>>>(tmp, (float*)d_out);
}

// Round 13
// 624.249 us; speedup vs baseline: 1.2740x; 1.2740x over previous
//
#include <hip/hip_runtime.h>
#include <math.h>
#include <limits.h>

#define HH 1280
#define WW 1920
#define OUT_H 427
#define OUT_W 640
#define SENT 0x7fff7fff   // packed (r,c) sentinel: r=c=0x7fff

typedef short short2v __attribute__((ext_vector_type(2)));

// d^2 between packed cell a=(r<<16|c) and packed owner P=(pi<<16|pj).
// Exact int32: max real d^2 = 1279^2+1919^2 = 5.3e6; SENT d^2 ~ 1.94e9 < 2^31.
// SENT never beats a real cur and ties with SENT cur (strict <) -> reproduces
// the reference's "skip SENT cand / INT_MAX for SENT cur" bit-exactly.
__device__ __forceinline__ int dot22(int a, int P) {
#if __has_builtin(__builtin_amdgcn_sdot2)
    short2v s = __builtin_bit_cast(short2v, a) - __builtin_bit_cast(short2v, P);
    return __builtin_amdgcn_sdot2(s, s, 0, false);
#else
    int dr = (a >> 16) - (P >> 16);
    int dc = (short)a - (short)P;
    return dr * dr + dc * dc;
#endif
}
// strict-< pick with carried d^2(cur)
#define PICK(P, cur, dcur, cand)                    \
    {                                               \
        int _d = dot22((cand), (P));                \
        if (_d < (dcur)) { (cur) = (cand); (dcur) = _d; } \
    }

// ---------------- scatter: project points, atomicAdd depth ----------------
// Reproduces XLA CPU dot lowering bit-exactly: plain mul/add (no FMA),
// ascending-k accumulation, translation added after.
__global__ void scatter_k(const float* __restrict__ pts,
                          const float* __restrict__ pose,
                          const float* __restrict__ extr,
                          const float* __restrict__ intr,
                          float* __restrict__ depth, int N) {
    #pragma clang fp contract(off)
    int t = blockIdx.x * blockDim.x + threadIdx.x;
    int b = blockIdx.y;
    if (t >= N) return;
    const float* p = pts + ((long)b * N + t) * 3;
    float x = p[0], y = p[1], z = p[2];
    const float* P = pose + b * 16;
    const float* E = extr + b * 16;
    const float* K = intr + b * 9;
    float wx = ((x*P[0] + y*P[1]) + z*P[2]) + P[3];
    float wy = ((x*P[4] + y*P[5]) + z*P[6]) + P[7];
    float wz = ((x*P[8] + y*P[9]) + z*P[10]) + P[11];
    float cx = ((wx*E[0] + wy*E[1]) + wz*E[2]) + E[3];
    float cy = ((wx*E[4] + wy*E[5]) + wz*E[6]) + E[7];
    float cz = ((wx*E[8] + wy*E[9]) + wz*E[10]) + E[11];
    float px = (cx*K[0] + cy*K[1]) + cz*K[2];
    float py = (cx*K[3] + cy*K[4]) + cz*K[5];
    float pz = (cx*K[6] + cy*K[7]) + cz*K[8];
    float u = px / pz, v = py / pz;
    int r = (int)floorf(v), c = (int)floorf(u);
    if (r >= 0 && r < HH && c >= 0 && c < WW) {
        float dv = sqrtf((x*x + y*y) + z*z);
        atomicAdd(depth + ((long)b * HH + r) * WW + c, dv);
    }
}

// ======== row-LDS staged JFA groups (one block per image row) ========
// 3-pass group, fixed dy: (dy,-k),(dy,0),(dy,+k) in reference order.
// FIRST: stage from depth canvas (fused init -> packed coords).
// k%4==0 dispatches take the x4-vectorized path (aligned int4 LDS reads,
// per-int4 bounds: j0,k both ==0 mod 4 so shifted quads are fully in or out).
template <bool FIRST>
__global__ __launch_bounds__(512)
void jfa3r_k(const void* __restrict__ inv_, int* __restrict__ out, int dy, int k) {
    __shared__ int rows[4][WW];
    int i = blockIdx.x, b = blockIdx.y;
    if (FIRST) {
        const float* dep = (const float*)inv_ + (long)b * HH * WW;
        #pragma unroll
        for (int t = 0; t < 4; ++t) {
            int r = i - t * dy;
            if (r >= 0 && r < HH) {
                const float4* src = reinterpret_cast<const float4*>(dep + (long)r * WW);
                for (int c4 = threadIdx.x; c4 < WW / 4; c4 += 512) {
                    float4 d = src[c4];
                    int4 v;
                    int c0 = c4 * 4, pb = r << 16;
                    v.x = (d.x != 0.0f) ? (pb | c0)       : SENT;
                    v.y = (d.y != 0.0f) ? (pb | (c0 + 1)) : SENT;
                    v.z = (d.z != 0.0f) ? (pb | (c0 + 2)) : SENT;
                    v.w = (d.w != 0.0f) ? (pb | (c0 + 3)) : SENT;
                    reinterpret_cast<int4*>(rows[t])[c4] = v;
                }
            } else {
                int4 sv; sv.x = sv.y = sv.z = sv.w = SENT;
                for (int c4 = threadIdx.x; c4 < WW / 4; c4 += 512)
                    reinterpret_cast<int4*>(rows[t])[c4] = sv;
            }
        }
    } else {
        const int* im = (const int*)inv_ + (long)b * HH * WW;
        #pragma unroll
        for (int t = 0; t < 4; ++t) {
            int r = i - t * dy;
            if (r >= 0 && r < HH) {
                const int4* src = reinterpret_cast<const int4*>(im + (long)r * WW);
                for (int c4 = threadIdx.x; c4 < WW / 4; c4 += 512)
                    reinterpret_cast<int4*>(rows[t])[c4] = src[c4];
            } else {
                int4 sv; sv.x = sv.y = sv.z = sv.w = SENT;
                for (int c4 = threadIdx.x; c4 < WW / 4; c4 += 512)
                    reinterpret_cast<int4*>(rows[t])[c4] = sv;
            }
        }
    }
    __syncthreads();
    bool rv1 = (unsigned)(i - dy)     < (unsigned)HH;
    bool rv2 = (unsigned)(i - 2 * dy) < (unsigned)HH;
    int* orow = out + ((long)b * HH + i) * WW;
    if ((k & 3) == 0) {
        // ---- vectorized x4 path ----
        int j0 = (int)threadIdx.x * 4;
        if (j0 < WW) {
            bool okP = (j0 + k) < WW;   // whole shifted quad in-bounds
            bool okM = (j0 - k) >= 0;
            int A0[4], A1[4], A2[4], A3[4], A1K[4], A2K[4], A1M[4], A2M[4];
            *(int4*)A0 = *(const int4*)&rows[0][j0];
            *(int4*)A1 = *(const int4*)&rows[1][j0];
            *(int4*)A2 = *(const int4*)&rows[2][j0];
            *(int4*)A3 = *(const int4*)&rows[3][j0];
            int4 s4; s4.x = s4.y = s4.z = s4.w = SENT;
            *(int4*)A1K = okP ? *(const int4*)&rows[1][j0 + k] : s4;
            *(int4*)A2K = okP ? *(const int4*)&rows[2][j0 + k] : s4;
            *(int4*)A1M = okM ? *(const int4*)&rows[1][j0 - k] : s4;
            *(int4*)A2M = okM ? *(const int4*)&rows[2][j0 - k] : s4;
            int res[4];
            #pragma unroll
            for (int p = 0; p < 4; ++p) {
                int j = j0 + p;
                int Pp = (i << 16) | j;
                int cur = A0[p];
                int dcur = dot22(cur, Pp);
                PICK(Pp, cur, dcur, A1K[p])
                int o1m = SENT;
                if (rv1) {
                    int Pm = ((i - dy) << 16) | j;
                    int a = A1[p];
                    int da = dot22(a, Pm);
                    PICK(Pm, a, da, A2K[p])
                    o1m = a;
                }
                PICK(Pp, cur, dcur, o1m)
                int o2q = SENT;
                if (rv1 && okM) {
                    int qj = j - k;
                    int Pq = ((i - dy) << 16) | qj;
                    int a0 = A1M[p];
                    int d0 = dot22(a0, Pq);
                    PICK(Pq, a0, d0, A2[p])
                    int a1 = SENT;
                    if (rv2) {
                        int Pq2 = ((i - 2 * dy) << 16) | qj;
                        a1 = A2M[p];
                        int d1 = dot22(a1, Pq2);
                        PICK(Pq2, a1, d1, A3[p])
                    }
                    PICK(Pq, a0, d0, a1)
                    o2q = a0;
                }
                PICK(Pp, cur, dcur, o2q)
                res[p] = cur;
            }
            *reinterpret_cast<int4*>(&orow[j0]) = *(const int4*)res;
        }
    } else {
        // ---- scalar path (k = 1, 2) ----
        for (int j = threadIdx.x; j < WW; j += 512) {
            bool jk = (j + k < WW);
            int Pp = (i << 16) | j;
            int cur = rows[0][j];
            int dcur = dot22(cur, Pp);
            int c1 = jk ? rows[1][j + k] : SENT;
            PICK(Pp, cur, dcur, c1)
            int o1m = SENT;
            if (rv1) {
                int Pm = ((i - dy) << 16) | j;
                int a = rows[1][j];
                int da = dot22(a, Pm);
                int c2 = jk ? rows[2][j + k] : SENT;
                PICK(Pm, a, da, c2)
                o1m = a;
            }
            PICK(Pp, cur, dcur, o1m)
            int o2q = SENT;
            int qj = j - k;
            if (rv1 && qj >= 0) {
                int Pq = ((i - dy) << 16) | qj;
                int a0 = rows[1][qj];
                int d0 = dot22(a0, Pq);
                PICK(Pq, a0, d0, rows[2][j])
                int a1 = SENT;
                if (rv2) {
                    int Pq2 = ((i - 2 * dy) << 16) | qj;
                    a1 = rows[2][qj];
                    int d1 = dot22(a1, Pq2);
                    PICK(Pq2, a1, d1, rows[3][j])
                }
                PICK(Pq, a0, d0, a1)
                o2q = a0;
            }
            PICK(Pp, cur, dcur, o2q)
            orow[j] = cur;
        }
    }
}

// 2-pass group dy=0: (0,-k),(0,+k) in reference order; row-local.
__global__ __launch_bounds__(512)
void jfa2r_k(const int* __restrict__ in, int* __restrict__ out, int k) {
    __shared__ int row[WW];
    int i = blockIdx.x, b = blockIdx.y;
    const int4* src = reinterpret_cast<const int4*>(in + ((long)b * HH + i) * WW);
    for (int c4 = threadIdx.x; c4 < WW / 4; c4 += 512)
        reinterpret_cast<int4*>(row)[c4] = src[c4];
    __syncthreads();
    int* orow = out + ((long)b * HH + i) * WW;
    if ((k & 3) == 0) {
        int j0 = (int)threadIdx.x * 4;
        if (j0 < WW) {
            bool okP = (j0 + k) < WW;
            bool okM = (j0 - k) >= 0;
            int A[4], APK[4], AMK[4];
            *(int4*)A = *(const int4*)&row[j0];
            int4 s4; s4.x = s4.y = s4.z = s4.w = SENT;
            *(int4*)APK = okP ? *(const int4*)&row[j0 + k] : s4;
            *(int4*)AMK = okM ? *(const int4*)&row[j0 - k] : s4;
            int res[4];
            #pragma unroll
            for (int p = 0; p < 4; ++p) {
                int j = j0 + p;
                int Pp = (i << 16) | j;
                int a = A[p];
                int cur = a;
                int dcur = dot22(cur, Pp);
                PICK(Pp, cur, dcur, APK[p])
                int o1m = SENT;
                if (okM) {
                    int qj = j - k;
                    int Pm = (i << 16) | qj;
                    int am = AMK[p];
                    int dm = dot22(am, Pm);
                    PICK(Pm, am, dm, a)
                    o1m = am;
                }
                PICK(Pp, cur, dcur, o1m)
                res[p] = cur;
            }
            *reinterpret_cast<int4*>(&orow[j0]) = *(const int4*)res;
        }
    } else {
        for (int j = threadIdx.x; j < WW; j += 512) {
            int Pp = (i << 16) | j;
            int a = row[j];
            int cur = a;
            int dcur = dot22(cur, Pp);
            int apk = (j + k < WW) ? row[j + k] : SENT;
            PICK(Pp, cur, dcur, apk)
            int o1m = SENT;
            int qj = j - k;
            if (qj >= 0) {
                int Pm = (i << 16) | qj;
                int am = row[qj];
                int dm = dot22(am, Pm);
                PICK(Pm, am, dm, a)
                o1m = am;
            }
            PICK(Pp, cur, dcur, o1m)
            orow[j] = cur;
        }
    }
}

// ------- fused compose + horizontal resize: one block per image row -------
__global__ __launch_bounds__(256)
void hresize_k(const float* __restrict__ depth,
               const int* __restrict__ nr,
               float* __restrict__ tmp) {
    __shared__ float fbuf[WW];
    __shared__ float dbuf[WW];
    int i = blockIdx.x, b = blockIdx.y;
    const float* dep = depth + (long)b * HH * WW;
    const float* drow = dep + (long)i * WW;
    const int* nrow = nr + ((long)b * HH + i) * WW;
    for (int j = threadIdx.x; j < WW; j += 256) {
        float dv = drow[j];
        float f, dist;
        if (dv != 0.0f) { f = dv; dist = 0.0f; }
        else {
            int nn = nrow[j];
            int rr, cc;
            if (nn == SENT) { rr = HH - 1; cc = WW - 1; }  // clip(BIG) path
            else { rr = nn >> 16; cc = nn & 0xffff; }
            f = dep[(long)rr * WW + cc];
            float drr = (float)i - (float)rr, dcc = (float)j - (float)cc;
            dist = sqrtf(drr * drr + dcc * dcc);
        }
        fbuf[j] = f; dbuf[j] = dist;
    }
    __syncthreads();
    const float inv = 3.0f;  // 1920/640
    for (int ow = threadIdx.x; ow < OUT_W; ow += 256) {
        float sf = (ow + 0.5f) * inv - 0.5f;
        int i0 = (int)ceilf(sf - inv);
        float a0 = 0.f, a1 = 0.f, wsum = 0.f;
        for (int k = 0; k < 7; ++k) {
            int iw = i0 + k;
            if (iw < 0 || iw >= WW) continue;
            float wgt = 1.0f - fabsf(sf - (float)iw) / inv;
            if (wgt <= 0.0f) continue;
            a0 += wgt * fbuf[iw]; a1 += wgt * dbuf[iw]; wsum += wgt;
        }
        long o = (((long)b * 2 + 0) * HH + i) * OUT_W + ow;
        tmp[o] = a0 / wsum;
        tmp[o + (long)HH * OUT_W] = a1 / wsum;
    }
}

// ---------------- vertical resize (H 1280->427) ----------------
__global__ void vresize_k(const float* __restrict__ tmp, float* __restrict__ out) {
    int ow = blockIdx.x * blockDim.x + threadIdx.x;
    int oh = blockIdx.y, bc = blockIdx.z;  // bc = b*2 + ch
    if (ow >= OUT_W) return;
    const float inv = (float)(1280.0 / 427.0);
    float sf = (oh + 0.5f) * inv - 0.5f;
    int i0 = (int)ceilf(sf - inv);
    float acc = 0.f, wsum = 0.f;
    const float* src = tmp + (long)bc * HH * OUT_W;
    for (int k = 0; k < 7; ++k) {
        int ih = i0 + k;
        if (ih < 0 || ih >= HH) continue;
        float wgt = 1.0f - fabsf(sf - (float)ih) / inv;
        if (wgt <= 0.0f) continue;
        acc += wgt * src[(long)ih * OUT_W + ow];
        wsum += wgt;
    }
    out[((long)bc * OUT_H + oh) * OUT_W + ow] = acc / wsum;
}

extern "C" void kernel_launch(void* const* d_in, const int* in_sizes, int n_in,
                              void* d_out, int out_size, void* d_ws, size_t ws_size,
                              hipStream_t stream) {
    const float* pts  = (const float*)d_in[0];
    const float* pose = (const float*)d_in[1];
    const float* extr = (const float*)d_in[2];
    const float* intr = (const float*)d_in[3];
    int B = in_sizes[1] / 16;
    int N = in_sizes[0] / (3 * B);

    char* ws = (char*)d_ws;
    size_t imgSz = (size_t)B * HH * WW;
    float* depth = (float*)ws;                  // B*H*W f32
    int*   nearA = (int*)(ws + imgSz * 4);      // B*H*W i32
    int*   nearB = (int*)(ws + imgSz * 8);      // B*H*W i32
    float* tmp   = (float*)(ws + imgSz * 12);   // B*2*H*OUT_W f32

    hipMemsetAsync(depth, 0, imgSz * sizeof(float), stream);

    dim3 bs(256);
    scatter_k<<<dim3((N + 255) / 256, B), bs, 0, stream>>>(pts, pose, extr, intr, depth, N);

    dim3 gr(HH, B);
    int* cur = nearA; int* nxt = nearB;
    // leading k=1 step: init fused into the first 3-pass group
    jfa3r_k<true><<<gr, 512, 0, stream>>>(depth, cur, -1, 1);
    jfa2r_k<<<gr, 512, 0, stream>>>(cur, nxt, 1);
    { int* t2 = cur; cur = nxt; nxt = t2; }
    jfa3r_k<false><<<gr, 512, 0, stream>>>(cur, nxt, +1, 1);
    { int* t2 = cur; cur = nxt; nxt = t2; }

    const int steps_rest[11] = {1024, 512, 256, 128, 64, 32, 16, 8, 4, 2, 1};
    for (int s = 0; s < 11; ++s) {
        int k = steps_rest[s];
        jfa3r_k<false><<<gr, 512, 0, stream>>>(cur, nxt, -k, k);
        { int* t2 = cur; cur = nxt; nxt = t2; }
        jfa2r_k<<<gr, 512, 0, stream>>>(cur, nxt, k);
        { int* t2 = cur; cur = nxt; nxt = t2; }
        jfa3r_k<false><<<gr, 512, 0, stream>>>(cur, nxt, +k, k);
        { int* t2 = cur; cur = nxt; nxt = t2; }
    }

    hresize_k<<<dim3(HH, B), bs, 0, stream>>>(depth, cur, tmp);
    vresize_k<<<dim3((OUT_W + 255) / 256, OUT_H, B * 2), bs, 0, stream>>>(tmp, (float*)d_out);
}

// Round 14
// 497.366 us; speedup vs baseline: 1.5990x; 1.2551x over previous
//
#include <hip/hip_runtime.h>
#include <math.h>
#include <limits.h>

#define HH 1280
#define WW 1920
#define OUT_H 427
#define OUT_W 640
#define SENT 0x7fff7fff   // packed (r,c) sentinel: r=c=0x7fff

typedef short short2v __attribute__((ext_vector_type(2)));

// d^2 between packed cell a=(r<<16|c) and packed owner P=(pi<<16|pj).
// Exact int32: max real d^2 = 1279^2+1919^2 = 5.3e6; SENT d^2 ~ 1.94e9 < 2^31.
// SENT never beats a real cur and ties with SENT cur (strict <) -> reproduces
// the reference's "skip SENT cand / INT_MAX for SENT cur" bit-exactly.
__device__ __forceinline__ int dot22(int a, int P) {
#if __has_builtin(__builtin_amdgcn_sdot2)
    short2v s = __builtin_bit_cast(short2v, a) - __builtin_bit_cast(short2v, P);
    return __builtin_amdgcn_sdot2(s, s, 0, false);
#else
    int dr = (a >> 16) - (P >> 16);
    int dc = (short)a - (short)P;
    return dr * dr + dc * dc;
#endif
}
// strict-< pick with carried d^2(cur)
#define PICK(P, cur, dcur, cand)                    \
    {                                               \
        int _d = dot22((cand), (P));                \
        if (_d < (dcur)) { (cur) = (cand); (dcur) = _d; } \
    }

// ---------------- scatter: project points, atomicAdd depth ----------------
// Reproduces XLA CPU dot lowering bit-exactly: plain mul/add (no FMA),
// ascending-k accumulation, translation added after.
__global__ void scatter_k(const float* __restrict__ pts,
                          const float* __restrict__ pose,
                          const float* __restrict__ extr,
                          const float* __restrict__ intr,
                          float* __restrict__ depth, int N) {
    #pragma clang fp contract(off)
    int t = blockIdx.x * blockDim.x + threadIdx.x;
    int b = blockIdx.y;
    if (t >= N) return;
    const float* p = pts + ((long)b * N + t) * 3;
    float x = p[0], y = p[1], z = p[2];
    const float* P = pose + b * 16;
    const float* E = extr + b * 16;
    const float* K = intr + b * 9;
    float wx = ((x*P[0] + y*P[1]) + z*P[2]) + P[3];
    float wy = ((x*P[4] + y*P[5]) + z*P[6]) + P[7];
    float wz = ((x*P[8] + y*P[9]) + z*P[10]) + P[11];
    float cx = ((wx*E[0] + wy*E[1]) + wz*E[2]) + E[3];
    float cy = ((wx*E[4] + wy*E[5]) + wz*E[6]) + E[7];
    float cz = ((wx*E[8] + wy*E[9]) + wz*E[10]) + E[11];
    float px = (cx*K[0] + cy*K[1]) + cz*K[2];
    float py = (cx*K[3] + cy*K[4]) + cz*K[5];
    float pz = (cx*K[6] + cy*K[7]) + cz*K[8];
    float u = px / pz, v = py / pz;
    int r = (int)floorf(v), c = (int)floorf(u);
    if (r >= 0 && r < HH && c >= 0 && c < WW) {
        float dv = sqrtf((x*x + y*y) + z*z);
        atomicAdd(depth + ((long)b * HH + r) * WW + c, dv);
    }
}

// ======== row-LDS staged JFA groups (one block per image row) ========

// --- fused G1 (dy=-k: P1,P2,P3) + G2 (dy=0: P4,P5) in one dispatch ---
// Stage input rows i, i+k, i+2k, i+3k (slots 0..3); compute G1 row i into
// g1row (LDS); sync; apply G2 row-locally; one store. Work-neutral fusion:
// G2 depends only on G1[i][j], G1[i][j+-k] -- all in-block.
template <bool FIRST>
__global__ __launch_bounds__(512)
void jfa12_k(const void* __restrict__ inv_, int* __restrict__ out, int k) {
    __shared__ int rows[4][WW];
    __shared__ int g1row[WW];
    int i = blockIdx.x, b = blockIdx.y;
    if (FIRST) {
        const float* dep = (const float*)inv_ + (long)b * HH * WW;
        #pragma unroll
        for (int t = 0; t < 4; ++t) {
            int r = i + t * k;
            if (r < HH) {
                const float4* src = reinterpret_cast<const float4*>(dep + (long)r * WW);
                for (int c4 = threadIdx.x; c4 < WW / 4; c4 += 512) {
                    float4 d = src[c4];
                    int4 v;
                    int c0 = c4 * 4, pb = r << 16;
                    v.x = (d.x != 0.0f) ? (pb | c0)       : SENT;
                    v.y = (d.y != 0.0f) ? (pb | (c0 + 1)) : SENT;
                    v.z = (d.z != 0.0f) ? (pb | (c0 + 2)) : SENT;
                    v.w = (d.w != 0.0f) ? (pb | (c0 + 3)) : SENT;
                    reinterpret_cast<int4*>(rows[t])[c4] = v;
                }
            } else {
                int4 sv; sv.x = sv.y = sv.z = sv.w = SENT;
                for (int c4 = threadIdx.x; c4 < WW / 4; c4 += 512)
                    reinterpret_cast<int4*>(rows[t])[c4] = sv;
            }
        }
    } else {
        const int* im = (const int*)inv_ + (long)b * HH * WW;
        #pragma unroll
        for (int t = 0; t < 4; ++t) {
            int r = i + t * k;
            if (r < HH) {
                const int4* src = reinterpret_cast<const int4*>(im + (long)r * WW);
                for (int c4 = threadIdx.x; c4 < WW / 4; c4 += 512)
                    reinterpret_cast<int4*>(rows[t])[c4] = src[c4];
            } else {
                int4 sv; sv.x = sv.y = sv.z = sv.w = SENT;
                for (int c4 = threadIdx.x; c4 < WW / 4; c4 += 512)
                    reinterpret_cast<int4*>(rows[t])[c4] = sv;
            }
        }
    }
    __syncthreads();
    // ---- G1 (dy=-k) for row i: verified jfa3r tree with i-dy = i+k ----
    bool rv1 = (i + k)     < HH;
    bool rv2 = (i + 2 * k) < HH;
    for (int j = threadIdx.x; j < WW; j += 512) {
        bool jk = (j + k < WW);
        int Pp = (i << 16) | j;
        int cur = rows[0][j];
        int dcur = dot22(cur, Pp);
        int c1 = jk ? rows[1][j + k] : SENT;
        PICK(Pp, cur, dcur, c1)
        int o1m = SENT;
        if (rv1) {
            int Pm = ((i + k) << 16) | j;
            int a = rows[1][j];
            int da = dot22(a, Pm);
            int c2 = jk ? rows[2][j + k] : SENT;
            PICK(Pm, a, da, c2)
            o1m = a;
        }
        PICK(Pp, cur, dcur, o1m)
        int o2q = SENT;
        int qj = j - k;
        if (rv1 && qj >= 0) {
            int Pq = ((i + k) << 16) | qj;
            int a0 = rows[1][qj];
            int d0 = dot22(a0, Pq);
            PICK(Pq, a0, d0, rows[2][j])
            int a1 = SENT;
            if (rv2) {
                int Pq2 = ((i + 2 * k) << 16) | qj;
                a1 = rows[2][qj];
                int d1 = dot22(a1, Pq2);
                PICK(Pq2, a1, d1, rows[3][j])
            }
            PICK(Pq, a0, d0, a1)
            o2q = a0;
        }
        PICK(Pp, cur, dcur, o2q)
        g1row[j] = cur;
    }
    __syncthreads();
    // ---- G2 (dy=0) row-local on g1row: verified jfa2r tree ----
    int* orow = out + ((long)b * HH + i) * WW;
    for (int j = threadIdx.x; j < WW; j += 512) {
        int Pp = (i << 16) | j;
        int a = g1row[j];
        int cur = a;
        int dcur = dot22(cur, Pp);
        int apk = (j + k < WW) ? g1row[j + k] : SENT;
        PICK(Pp, cur, dcur, apk)
        int o1m = SENT;
        int qj = j - k;
        if (qj >= 0) {
            int Pm = (i << 16) | qj;
            int am = g1row[qj];
            int dm = dot22(am, Pm);
            PICK(Pm, am, dm, a)
            o1m = am;
        }
        PICK(Pp, cur, dcur, o1m)
        orow[j] = cur;
    }
}

// --- G3 group (dy=+k: P6,P7,P8), verified R10 kernel (scalar picks) ---
__global__ __launch_bounds__(512)
void jfa3r_k(const int* __restrict__ inv_, int* __restrict__ out, int dy, int k) {
    __shared__ int rows[4][WW];
    int i = blockIdx.x, b = blockIdx.y;
    const int* im = inv_ + (long)b * HH * WW;
    #pragma unroll
    for (int t = 0; t < 4; ++t) {
        int r = i - t * dy;
        if (r >= 0 && r < HH) {
            const int4* src = reinterpret_cast<const int4*>(im + (long)r * WW);
            for (int c4 = threadIdx.x; c4 < WW / 4; c4 += 512)
                reinterpret_cast<int4*>(rows[t])[c4] = src[c4];
        } else {
            int4 sv; sv.x = sv.y = sv.z = sv.w = SENT;
            for (int c4 = threadIdx.x; c4 < WW / 4; c4 += 512)
                reinterpret_cast<int4*>(rows[t])[c4] = sv;
        }
    }
    __syncthreads();
    bool rv1 = (unsigned)(i - dy)     < (unsigned)HH;
    bool rv2 = (unsigned)(i - 2 * dy) < (unsigned)HH;
    int* orow = out + ((long)b * HH + i) * WW;
    for (int j = threadIdx.x; j < WW; j += 512) {
        bool jk = (j + k < WW);
        int Pp = (i << 16) | j;
        int cur = rows[0][j];
        int dcur = dot22(cur, Pp);
        int c1 = jk ? rows[1][j + k] : SENT;
        PICK(Pp, cur, dcur, c1)
        int o1m = SENT;
        if (rv1) {
            int Pm = ((i - dy) << 16) | j;
            int a = rows[1][j];
            int da = dot22(a, Pm);
            int c2 = jk ? rows[2][j + k] : SENT;
            PICK(Pm, a, da, c2)
            o1m = a;
        }
        PICK(Pp, cur, dcur, o1m)
        int o2q = SENT;
        int qj = j - k;
        if (rv1 && qj >= 0) {
            int Pq = ((i - dy) << 16) | qj;
            int a0 = rows[1][qj];
            int d0 = dot22(a0, Pq);
            PICK(Pq, a0, d0, rows[2][j])
            int a1 = SENT;
            if (rv2) {
                int Pq2 = ((i - 2 * dy) << 16) | qj;
                a1 = rows[2][qj];
                int d1 = dot22(a1, Pq2);
                PICK(Pq2, a1, d1, rows[3][j])
            }
            PICK(Pq, a0, d0, a1)
            o2q = a0;
        }
        PICK(Pp, cur, dcur, o2q)
        orow[j] = cur;
    }
}

// ------- fused compose + horizontal resize: one block per image row -------
__global__ __launch_bounds__(256)
void hresize_k(const float* __restrict__ depth,
               const int* __restrict__ nr,
               float* __restrict__ tmp) {
    __shared__ float fbuf[WW];
    __shared__ float dbuf[WW];
    int i = blockIdx.x, b = blockIdx.y;
    const float* dep = depth + (long)b * HH * WW;
    const float* drow = dep + (long)i * WW;
    const int* nrow = nr + ((long)b * HH + i) * WW;
    for (int j = threadIdx.x; j < WW; j += 256) {
        float dv = drow[j];
        float f, dist;
        if (dv != 0.0f) { f = dv; dist = 0.0f; }
        else {
            int nn = nrow[j];
            int rr, cc;
            if (nn == SENT) { rr = HH - 1; cc = WW - 1; }  // clip(BIG) path
            else { rr = nn >> 16; cc = nn & 0xffff; }
            f = dep[(long)rr * WW + cc];
            float drr = (float)i - (float)rr, dcc = (float)j - (float)cc;
            dist = sqrtf(drr * drr + dcc * dcc);
        }
        fbuf[j] = f; dbuf[j] = dist;
    }
    __syncthreads();
    const float inv = 3.0f;  // 1920/640
    for (int ow = threadIdx.x; ow < OUT_W; ow += 256) {
        float sf = (ow + 0.5f) * inv - 0.5f;
        int i0 = (int)ceilf(sf - inv);
        float a0 = 0.f, a1 = 0.f, wsum = 0.f;
        for (int k = 0; k < 7; ++k) {
            int iw = i0 + k;
            if (iw < 0 || iw >= WW) continue;
            float wgt = 1.0f - fabsf(sf - (float)iw) / inv;
            if (wgt <= 0.0f) continue;
            a0 += wgt * fbuf[iw]; a1 += wgt * dbuf[iw]; wsum += wgt;
        }
        long o = (((long)b * 2 + 0) * HH + i) * OUT_W + ow;
        tmp[o] = a0 / wsum;
        tmp[o + (long)HH * OUT_W] = a1 / wsum;
    }
}

// ---------------- vertical resize (H 1280->427) ----------------
__global__ void vresize_k(const float* __restrict__ tmp, float* __restrict__ out) {
    int ow = blockIdx.x * blockDim.x + threadIdx.x;
    int oh = blockIdx.y, bc = blockIdx.z;  // bc = b*2 + ch
    if (ow >= OUT_W) return;
    const float inv = (float)(1280.0 / 427.0);
    float sf = (oh + 0.5f) * inv - 0.5f;
    int i0 = (int)ceilf(sf - inv);
    float acc = 0.f, wsum = 0.f;
    const float* src = tmp + (long)bc * HH * OUT_W;
    for (int k = 0; k < 7; ++k) {
        int ih = i0 + k;
        if (ih < 0 || ih >= HH) continue;
        float wgt = 1.0f - fabsf(sf - (float)ih) / inv;
        if (wgt <= 0.0f) continue;
        acc += wgt * src[(long)ih * OUT_W + ow];
        wsum += wgt;
    }
    out[((long)bc * OUT_H + oh) * OUT_W + ow] = acc / wsum;
}

extern "C" void kernel_launch(void* const* d_in, const int* in_sizes, int n_in,
                              void* d_out, int out_size, void* d_ws, size_t ws_size,
                              hipStream_t stream) {
    const float* pts  = (const float*)d_in[0];
    const float* pose = (const float*)d_in[1];
    const float* extr = (const float*)d_in[2];
    const float* intr = (const float*)d_in[3];
    int B = in_sizes[1] / 16;
    int N = in_sizes[0] / (3 * B);

    char* ws = (char*)d_ws;
    size_t imgSz = (size_t)B * HH * WW;
    float* depth = (float*)ws;                  // B*H*W f32
    int*   nearA = (int*)(ws + imgSz * 4);      // B*H*W i32
    int*   nearB = (int*)(ws + imgSz * 8);      // B*H*W i32
    float* tmp   = (float*)(ws + imgSz * 12);   // B*2*H*OUT_W f32

    hipMemsetAsync(depth, 0, imgSz * sizeof(float), stream);

    dim3 bs(256);
    scatter_k<<<dim3((N + 255) / 256, B), bs, 0, stream>>>(pts, pose, extr, intr, depth, N);

    dim3 gr(HH, B);
    int* cur = nearA; int* nxt = nearB;
    // leading k=1 step: init fused into G1+G2
    jfa12_k<true><<<gr, 512, 0, stream>>>(depth, cur, 1);
    jfa3r_k<<<gr, 512, 0, stream>>>(cur, nxt, +1, 1);
    { int* t2 = cur; cur = nxt; nxt = t2; }

    const int steps_rest[11] = {1024, 512, 256, 128, 64, 32, 16, 8, 4, 2, 1};
    for (int s = 0; s < 11; ++s) {
        int k = steps_rest[s];
        jfa12_k<false><<<gr, 512, 0, stream>>>(cur, nxt, k);
        { int* t2 = cur; cur = nxt; nxt = t2; }
        jfa3r_k<<<gr, 512, 0, stream>>>(cur, nxt, +k, k);
        { int* t2 = cur; cur = nxt; nxt = t2; }
    }

    hresize_k<<<dim3(HH, B), bs, 0, stream>>>(depth, cur, tmp);
    vresize_k<<<dim3((OUT_W + 255) / 256, OUT_H, B * 2), bs, 0, stream>>>(tmp, (float*)d_out);
}